// Round 1
// 300.742 us; speedup vs baseline: 1.0832x; 1.0832x over previous
//
#include <hip/hip_runtime.h>
#include <hip/hip_bf16.h>
#include <stdint.h>

// ---------------------------------------------------------------------------
// DiagonalElman on MI355X (gfx950)
//   W_comb = W_x @ W_in                  (small bf16 GEMM; xw = x @ W_comb^T)
//   [xproj | xw] = x @ [W_in ; W_comb]^T (one fused bf16 GEMM, bf16 out)
//   scan: h_t = tanh(xw_t + a*h_{t-1} + b); cell = h * silu(xproj + b_gate)
//   out    = cell @ W_out^T              (bf16 GEMM, fp32 out -> d_out)
//
// R6: big GEMMs moved to a 256x256-tile LDS-staged pipeline (T3+T4+T5 from
// the CDNA4 catalog): BK=32, 3 LDS buffers (96 KB), 8 waves (2Mx4N),
// 2 phases/K-tile x 16 MFMA, global_load_lds_dwordx4 staging 2 tiles ahead,
// counted s_waitcnt vmcnt(4) (never 0 in steady state), raw s_barrier,
// s_setprio around MFMA clusters. Operands stay in fragment order in global
// memory, so LDS staging is linear (wave-uniform base + lane*16) and
// ds_read_b128 readback is lane-contiguous (2-way bank aliasing = free).
// Fragment flat layout for [R x K] (16B units):
//   unit = (rb*KB + kb)*64 + lane,  rb=r>>4, kb=k>>5,
//   lane = (r&15) | (((k>>3)&3)<<4), elem j = k&7.
// ---------------------------------------------------------------------------

typedef __bf16 bf16x8 __attribute__((ext_vector_type(8)));
typedef float  f32x4  __attribute__((ext_vector_type(4)));

#define AS1 __attribute__((address_space(1)))
#define AS3 __attribute__((address_space(3)))

__device__ __forceinline__ unsigned short f2bf(float f) {
  uint32_t u = __float_as_uint(f);
  uint32_t r = (u + 0x7FFFu + ((u >> 16) & 1u)) >> 16;
  return (unsigned short)r;
}
__device__ __forceinline__ float bf2f(uint32_t h) {
  return __uint_as_float(h << 16);
}
__device__ __forceinline__ float tanh_fast(float x) {
  float e = __expf(2.0f * x);
  return 1.0f - 2.0f / (e + 1.0f);
}

// ---------------------------------------------------------------------------
// fp32 [R x K] row-major -> bf16 fragment order. grid = R*K/2048 blocks.
// ---------------------------------------------------------------------------
__global__ __launch_bounds__(256) void frag_f32(
    const float* __restrict__ W, unsigned short* __restrict__ out, int K, int KB) {
  const int u = blockIdx.x * 256 + threadIdx.x;  // 16B unit index
  const int lane = u & 63;
  const int grp  = u >> 6;
  const int n = (grp / KB) * 16 + (lane & 15);
  const int k = (grp % KB) * 32 + ((lane >> 4) & 3) * 8;
  const float4* p = (const float4*)(W + (size_t)n * K + k);
  float4 a = p[0], b = p[1];
  union { unsigned short us[8]; uint4 v; } r;
  r.us[0] = f2bf(a.x); r.us[1] = f2bf(a.y); r.us[2] = f2bf(a.z); r.us[3] = f2bf(a.w);
  r.us[4] = f2bf(b.x); r.us[5] = f2bf(b.y); r.us[6] = f2bf(b.z); r.us[7] = f2bf(b.w);
  *(uint4*)(out + (size_t)u * 8) = r.v;
}

// transposed fp32 source: frag(n,k) = W[k*N + n]
__global__ __launch_bounds__(256) void frag_f32_T(
    const float* __restrict__ W, unsigned short* __restrict__ out, int N, int KB) {
  const int u = blockIdx.x * 256 + threadIdx.x;
  const int lane = u & 63;
  const int grp  = u >> 6;
  const int n = (grp / KB) * 16 + (lane & 15);
  const int k = (grp % KB) * 32 + ((lane >> 4) & 3) * 8;
  union { unsigned short us[8]; uint4 v; } r;
#pragma unroll
  for (int j = 0; j < 8; ++j) r.us[j] = f2bf(W[(size_t)(k + j) * N + n]);
  *(uint4*)(out + (size_t)u * 8) = r.v;
}

// bf16 row-major source -> fragment order
__global__ __launch_bounds__(256) void frag_bf16(
    const unsigned short* __restrict__ W, unsigned short* __restrict__ out,
    int K, int KB) {
  const int u = blockIdx.x * 256 + threadIdx.x;
  const int lane = u & 63;
  const int grp  = u >> 6;
  const int n = (grp / KB) * 16 + (lane & 15);
  const int k = (grp % KB) * 32 + ((lane >> 4) & 3) * 8;
  *(uint4*)(out + (size_t)u * 8) = *(const uint4*)(W + (size_t)n * K + k);
}

// ---------------------------------------------------------------------------
// Small bf16 MFMA GEMM (128x128 tile, register-streaming, no LDS).
// Kept for W_comb = W_x @ W_in (grid too small for the 256^2 kernel).
// ---------------------------------------------------------------------------
#define BM 128
#define BN 128

template <int SM>
__global__ __launch_bounds__(256) void gemm_frag(
    const unsigned short* __restrict__ Af, const unsigned short* __restrict__ Bf,
    void* __restrict__ Cv, int M, int N, int K) {
  const int tid  = threadIdx.x;
  const int lane = tid & 63;
  const int wave = tid >> 6;
  const int wrow = wave >> 1;
  const int wcol = wave & 1;
  const int rowBase = blockIdx.x * BM;
  const int colBase = blockIdx.y * BN;
  const int q   = lane >> 4;
  const int r16 = lane & 15;
  const int KB  = K >> 5;

  const unsigned short* ap[4];
  const unsigned short* bp[4];
#pragma unroll
  for (int i = 0; i < 4; ++i) {
    const int rb = (rowBase >> 4) + wrow * 4 + i;
    const int nb = (colBase >> 4) + wcol * 4 + i;
    ap[i] = Af + ((size_t)rb * KB * 64 + lane) * 8;
    bp[i] = Bf + ((size_t)nb * KB * 64 + lane) * 8;
  }

  f32x4 acc[4][4] = {};
  bf16x8 a0[4], b0[4];
#pragma unroll
  for (int i = 0; i < 4; ++i) {
    a0[i] = *(const bf16x8*)ap[i];
    b0[i] = *(const bf16x8*)bp[i];
  }

  for (int kb = 0; kb < KB; ++kb) {
    const size_t noff = (size_t)((kb + 1 < KB) ? kb + 1 : kb) * 512;
    bf16x8 a1[4], b1[4];
#pragma unroll
    for (int i = 0; i < 4; ++i) {
      a1[i] = *(const bf16x8*)(ap[i] + noff);
      b1[i] = *(const bf16x8*)(bp[i] + noff);
    }
#pragma unroll
    for (int i = 0; i < 4; ++i)
#pragma unroll
      for (int j = 0; j < 4; ++j)
        acc[i][j] = __builtin_amdgcn_mfma_f32_16x16x32_bf16(a0[i], b0[j], acc[i][j], 0, 0, 0);
#pragma unroll
    for (int i = 0; i < 4; ++i) { a0[i] = a1[i]; b0[i] = b1[i]; }
  }

  // epilogue: C/D layout col = lane&15, row = (lane>>4)*4 + reg
#pragma unroll
  for (int i = 0; i < 4; ++i) {
#pragma unroll
    for (int j = 0; j < 4; ++j) {
#pragma unroll
      for (int rg = 0; rg < 4; ++rg) {
        long long row = rowBase + wrow * 64 + i * 16 + q * 4 + rg;
        long long col = colBase + wcol * 64 + j * 16 + r16;
        float v = acc[i][j][rg];
        if (SM == 0) ((float*)Cv)[row * (long long)N + col] = v;
        else ((unsigned short*)Cv)[row * (long long)N + col] = f2bf(v);
      }
    }
  }
}

// ---------------------------------------------------------------------------
// 256x256-tile LDS-pipelined bf16 MFMA GEMM. C[m,n] = sum_k A[m,k]*B[n,k].
// A,B in fragment order. M%256==0, N%256==0, K%32==0, K/32 >= 2.
// 512 thr = 8 waves (2 M-waves x 4 N-waves), wave owns 128x64 output.
// BK=32 (1 kb), 3 LDS buffers x (A 16KB + B 16KB) = 96 KB.
// Pipeline: during tile t, stage tile t+2 into buf (t+2)%3:
//   phase 0: ds_read b[0..3],a[0..3]; stage A(t+2); bar; setprio; 16 MFMA
//   phase 1: ds_read a2[0..3];        stage B(t+2); bar; setprio; 16 MFMA
//   boundary: vmcnt(4)  (tile t+1 landed, t+2's 4 loads stay in flight); bar
// ---------------------------------------------------------------------------
template <int SM>
__global__ __launch_bounds__(512, 2) void gemm256(
    const unsigned short* __restrict__ Af, const unsigned short* __restrict__ Bf,
    void* __restrict__ Cv, int N, int K) {
  __shared__ __attribute__((aligned(128))) char smem[98304];
  const int tid  = threadIdx.x;
  const int lane = tid & 63;
  const int w    = tid >> 6;   // 0..7
  const int wr   = w >> 2;     // 0..1  (M half)
  const int wc   = w & 3;      // 0..3  (N quarter)
  const int KB   = K >> 5;
  const int NT   = KB;
  const int rbBase = blockIdx.x << 4;   // 16 row-blocks per tile
  const int nbBase = blockIdx.y << 4;

  const char* Ab = (const char*)Af;
  const char* Bb = (const char*)Bf;

  f32x4 acc[8][4] = {};

  // wave w stages groups {2w, 2w+1}: global src is per-lane contiguous
  // (base + lane*16), LDS dst is wave-uniform base (HW adds lane*16).
#define STAGE_A(sb, tt)                                                         \
  {                                                                             \
    _Pragma("unroll")                                                           \
    for (int i_ = 0; i_ < 2; ++i_) {                                            \
      const int g_ = w * 2 + i_;                                                \
      const size_t go_ = (((size_t)(rbBase + g_) * KB + (size_t)(tt)) << 10) +  \
                         (size_t)(lane << 4);                                   \
      __builtin_amdgcn_global_load_lds((AS1 void*)(Ab + go_),                   \
          (AS3 void*)(smem + (sb) * 32768 + (g_ << 10)), 16, 0, 0);             \
    }                                                                           \
  }
#define STAGE_B(sb, tt)                                                         \
  {                                                                             \
    _Pragma("unroll")                                                           \
    for (int i_ = 0; i_ < 2; ++i_) {                                            \
      const int g_ = w * 2 + i_;                                                \
      const size_t go_ = (((size_t)(nbBase + g_) * KB + (size_t)(tt)) << 10) +  \
                         (size_t)(lane << 4);                                   \
      __builtin_amdgcn_global_load_lds((AS1 void*)(Bb + go_),                   \
          (AS3 void*)(smem + (sb) * 32768 + 16384 + (g_ << 10)), 16, 0, 0);     \
    }                                                                           \
  }

  // prologue: tile0 -> buf0, tile1 -> buf1; publish buf0.
  STAGE_A(0, 0); STAGE_B(0, 0);
  STAGE_A(1, 1); STAGE_B(1, 1);
  asm volatile("s_waitcnt vmcnt(4)" ::: "memory");  // tile0's 4 loads landed
  asm volatile("s_barrier" ::: "memory");

  int buf = 0;
  for (int t = 0; t < NT; ++t) {
    const char* LA = smem + buf * 32768;
    const char* LB = LA + 16384;
    const int sbuf = (buf == 0) ? 2 : buf - 1;     // == (t+2)%3
    bf16x8 a[4], b[4], a2[4];

    // ---- phase 0: rb[wr*8 .. wr*8+3] x nb[wc*4 .. wc*4+3]
#pragma unroll
    for (int j = 0; j < 4; ++j)
      b[j] = *(const bf16x8*)(LB + (((wc << 2) + j) << 10) + (lane << 4));
#pragma unroll
    for (int i = 0; i < 4; ++i)
      a[i] = *(const bf16x8*)(LA + (((wr << 3) + i) << 10) + (lane << 4));
    if (t + 2 < NT) STAGE_A(sbuf, t + 2);
    asm volatile("s_barrier" ::: "memory");
    __builtin_amdgcn_s_setprio(1);
#pragma unroll
    for (int i = 0; i < 4; ++i)
#pragma unroll
      for (int j = 0; j < 4; ++j)
        acc[i][j] = __builtin_amdgcn_mfma_f32_16x16x32_bf16(a[i], b[j], acc[i][j], 0, 0, 0);
    __builtin_amdgcn_s_setprio(0);
    asm volatile("s_barrier" ::: "memory");

    // ---- phase 1: rb[wr*8+4 .. wr*8+7] x same nb (b reused in regs)
#pragma unroll
    for (int i = 0; i < 4; ++i)
      a2[i] = *(const bf16x8*)(LA + (((wr << 3) + 4 + i) << 10) + (lane << 4));
    if (t + 2 < NT) STAGE_B(sbuf, t + 2);
    asm volatile("s_barrier" ::: "memory");
    __builtin_amdgcn_s_setprio(1);
#pragma unroll
    for (int i = 0; i < 4; ++i)
#pragma unroll
      for (int j = 0; j < 4; ++j)
        acc[4 + i][j] = __builtin_amdgcn_mfma_f32_16x16x32_bf16(a2[i], b[j], acc[4 + i][j], 0, 0, 0);
    __builtin_amdgcn_s_setprio(0);

    // ---- tile boundary: publish tile t+1; keep tile t+2's loads in flight
    if (t + 2 < NT) {
      asm volatile("s_waitcnt vmcnt(4)" ::: "memory");
    } else if (t + 1 < NT) {
      asm volatile("s_waitcnt vmcnt(0)" ::: "memory");  // tail only
    }
    asm volatile("s_barrier" ::: "memory");
    buf = (buf == 2) ? 0 : buf + 1;
  }
#undef STAGE_A
#undef STAGE_B

  // epilogue: C/D layout col = lane&15, row = (lane>>4)*4 + reg
  const int q = lane >> 4, r16 = lane & 15;
#pragma unroll
  for (int i = 0; i < 8; ++i) {
#pragma unroll
    for (int j = 0; j < 4; ++j) {
#pragma unroll
      for (int rg = 0; rg < 4; ++rg) {
        long long row = (long long)blockIdx.x * 256 + wr * 128 + i * 16 + q * 4 + rg;
        long long col = (long long)blockIdx.y * 256 + wc * 64 + j * 16 + r16;
        float v = acc[i][j][rg];
        if (SM == 0) ((float*)Cv)[row * (long long)N + col] = v;
        else ((unsigned short*)Cv)[row * (long long)N + col] = f2bf(v);
      }
    }
  }
}

// ---------------------------------------------------------------------------
// Chunked diagonal scan, 2 channels/thread, bf16 in/out.
// xcat: [B*T, 2D] row-major, cols 0..D-1 = xproj, D..2D-1 = xw.
// cell written in A-fragment order (feeds the out-GEMM directly).
// ---------------------------------------------------------------------------
__global__ __launch_bounds__(256) void scan_kernel2(
    const unsigned short* __restrict__ xcat,
    const float* __restrict__ h0, const float* __restrict__ araw,
    const float* __restrict__ bvec, const float* __restrict__ bgate,
    unsigned short* __restrict__ cell, float* __restrict__ hfin,
    int Bv, int T, int D, int NC, int CH, int WARM) {
  const int idx = blockIdx.x * 256 + threadIdx.x;
  const int D2  = D >> 1;
  const int BD2 = Bv * D2;
  const int c = idx / BD2;
  if (c >= NC) return;
  const int ld2 = idx - c * BD2;
  const int b = ld2 / D2;
  const int d = (ld2 - b * D2) * 2;

  const float2 ar = *(const float2*)&araw[d];
  const float ax = 1.0f / (1.0f + __expf(-ar.x));
  const float ay = 1.0f / (1.0f + __expf(-ar.y));
  const float2 bb = *(const float2*)&bvec[d];
  const float2 bg = *(const float2*)&bgate[d];

  const int tb = c * CH;
  const int te = (tb + CH < T) ? (tb + CH) : T;
  int t0 = tb - WARM;
  float hx, hy;
  if (t0 <= 0) {
    t0 = 0;
    float2 h00 = *(const float2*)&h0[b * D + d];
    hx = h00.x; hy = h00.y;
  } else { hx = 0.0f; hy = 0.0f; }

  const int N2 = 2 * D;
  long long off = ((long long)b * T + t0) * N2 + D + d;   // xw column
  for (int t = t0; t < tb; ++t) {                          // warm-up
    uint32_t w2 = *(const uint32_t*)&xcat[off];
    hx = tanh_fast(__builtin_fmaf(ax, hx, bf2f(w2 & 0xffffu) + bb.x));
    hy = tanh_fast(__builtin_fmaf(ay, hy, bf2f(w2 >> 16) + bb.y));
    off += N2;
  }
  long long offp = ((long long)b * T + tb) * N2 + d;       // xproj column
  // cell fragment-order address: m = b*T + t
  const int KBS = D * 16;                                  // (D>>5)*512
  const int dconst = (d >> 5) * 512 + ((d >> 3) & 3) * 128 + (d & 7);
  int m = b * T + tb;
  long long offc = (long long)(m >> 4) * KBS + (m & 15) * 8 + dconst;
  for (int t = tb; t < te; ++t) {
    uint32_t w2 = *(const uint32_t*)&xcat[off];
    uint32_t p2 = *(const uint32_t*)&xcat[offp];
    hx = tanh_fast(__builtin_fmaf(ax, hx, bf2f(w2 & 0xffffu) + bb.x));
    hy = tanh_fast(__builtin_fmaf(ay, hy, bf2f(w2 >> 16) + bb.y));
    float zx = bf2f(p2 & 0xffffu) + bg.x;
    float zy = bf2f(p2 >> 16) + bg.y;
    float ox = hx * zx / (1.0f + __expf(-zx));
    float oy = hy * zy / (1.0f + __expf(-zy));
    *(uint32_t*)&cell[offc] = (uint32_t)f2bf(ox) | ((uint32_t)f2bf(oy) << 16);
    off += N2; offp += N2;
    ++m;
    offc += 8;
    if ((m & 15) == 0) offc += (long long)KBS - 128;
  }
  if (te == T) {
    float2 hv; hv.x = hx; hv.y = hy;
    *(float2*)&hfin[b * D + d] = hv;
  }
}

// ---------------------------------------------------------------------------
extern "C" void kernel_launch(void* const* d_in, const int* in_sizes, int n_in,
                              void* d_out, int out_size, void* d_ws, size_t ws_size,
                              hipStream_t stream) {
  const float* x         = (const float*)d_in[0];
  const float* h0        = (const float*)d_in[1];
  const float* W_in      = (const float*)d_in[2];
  const float* W_x       = (const float*)d_in[3];
  const float* alpha_raw = (const float*)d_in[4];
  const float* b         = (const float*)d_in[5];
  const float* b_gate    = (const float*)d_in[6];
  const float* W_out     = (const float*)d_in[7];

  const int D  = in_sizes[4];
  const int BD = in_sizes[1];
  const int Bv = BD / D;
  const int M  = in_sizes[0] / D;   // B*T
  const int T  = M / Bv;
  const int KB = D >> 5;

  float* out  = (float*)d_out;                 // [M, D]
  float* hfin = out + (long long)M * D;        // [B, D]

  const size_t szXf  = (size_t)M * D * 2;      // bf16 frag [M,K=D]
  const size_t szCat = (size_t)M * D * 4;      // bf16 [M,2D] row-major
  const size_t szW   = (size_t)D * D * 2;      // bf16 [D,D]

  char* ws = (char*)d_ws;
  unsigned short* xfrag = (unsigned short*)ws; ws += szXf;
  unsigned short* xcat  = (unsigned short*)ws; ws += szCat;
  unsigned short* WcatF = (unsigned short*)ws; ws += 2 * szW;  // frag [2D, K=D]
  unsigned short* WoutF = (unsigned short*)ws; ws += szW;      // frag [D, K=D]
  // temporaries aliased inside xcat (dead before fused GEMM writes xcat):
  unsigned short* WxF    = xcat;
  unsigned short* WinTF  = xcat + (size_t)D * D;
  unsigned short* WcombR = xcat + 2 * (size_t)D * D;
  unsigned short* cell   = xfrag;              // xfrag dead after fused GEMM
  unsigned short* WcombF = WcatF + (size_t)D * D;

  const int xBlocks = (int)((size_t)M * D / 2048);
  const int wBlocks = (int)((size_t)D * D / 2048);

  frag_f32<<<xBlocks, 256, 0, stream>>>(x, xfrag, D, KB);
  frag_f32<<<wBlocks, 256, 0, stream>>>(W_x, WxF, D, KB);
  frag_f32_T<<<wBlocks, 256, 0, stream>>>(W_in, WinTF, D, KB);
  frag_f32<<<wBlocks, 256, 0, stream>>>(W_in, WcatF, D, KB);
  frag_f32<<<wBlocks, 256, 0, stream>>>(W_out, WoutF, D, KB);

  // W_comb = W_x @ W_in  (row-major bf16 out), then swizzle into WcatF 2nd half
  gemm_frag<1><<<dim3(D / BM, D / BN), 256, 0, stream>>>(WxF, WinTF, WcombR, D, D, D);
  frag_bf16<<<wBlocks, 256, 0, stream>>>(WcombR, WcombF, D, KB);

  // [xproj | xw] = x @ Wcat^T : M x 2D (row-major bf16 out) — 256^2 pipeline
  gemm256<1><<<dim3(M / 256, (2 * D) / 256), 512, 0, stream>>>(xfrag, WcatF, xcat, 2 * D, D);

  const int CH = 32;
  const int WARM = 16;
  const int NC = (T + CH - 1) / CH;
  const int total2 = NC * (BD >> 1);
  scan_kernel2<<<(total2 + 255) / 256, 256, 0, stream>>>(
      xcat, h0, alpha_raw, b, b_gate, cell, hfin, Bv, T, D, NC, CH, WARM);

  // out = cell @ W_out^T (fp32 out) — 256^2 pipeline
  gemm256<0><<<dim3(M / 256, D / 256), 512, 0, stream>>>(cell, WoutF, out, M > 0 ? D : D, D);
}